// Round 4
// baseline (134.258 us; speedup 1.0000x reference)
//
#include <hip/hip_runtime.h>
#include <hip/hip_bf16.h>

// Problem constants
#define B 4
#define N 2048
#define D 512
#define H 8
#define DH 64
#define ROWS (B * N)        // 8192
#define WIN 64              // r<=0.764 -> r^64 ~ 3e-8
#define QB 8                // query rows per wave in attn_sweep

using bf16x8 = __attribute__((ext_vector_type(8))) short;  // 8 bf16 (4 VGPRs)
using f32x4  = __attribute__((ext_vector_type(4))) float;  // MFMA accumulator

static __device__ __forceinline__ unsigned short f2bf(float f) {
    unsigned u = __builtin_bit_cast(unsigned, f);
    u += 0x7fffu + ((u >> 16) & 1u);        // round-to-nearest-even
    return (unsigned short)(u >> 16);
}

// ---------------- x f32 -> bf16 (8 elems/thread) ------------------------------
__global__ __launch_bounds__(256) void cvt_x(const float* __restrict__ x,
                                             unsigned short* __restrict__ xbf) {
    const size_t t = (size_t)blockIdx.x * 256 + threadIdx.x;
    const float4* p = reinterpret_cast<const float4*>(x) + t * 2;
    const float4 a = p[0], b = p[1];
    ushort4 lo, hi;
    lo.x = f2bf(a.x); lo.y = f2bf(a.y); lo.z = f2bf(a.z); lo.w = f2bf(a.w);
    hi.x = f2bf(b.x); hi.y = f2bf(b.y); hi.z = f2bf(b.z); hi.w = f2bf(b.w);
    ushort4* q = reinterpret_cast<ushort4*>(xbf) + t * 2;
    q[0] = lo; q[1] = hi;
}

// ---------------- W (512x512 f32, KxN) -> W^T (NxK bf16) ----------------------
__global__ __launch_bounds__(256) void transpose_cvt(const float* __restrict__ Wv,
                                                     const float* __restrict__ Wo,
                                                     unsigned short* __restrict__ WvT,
                                                     unsigned short* __restrict__ WoT) {
    const float* src = blockIdx.z ? Wo : Wv;
    unsigned short* dst = blockIdx.z ? WoT : WvT;
    __shared__ float tile[64][65];
    const int n0 = blockIdx.x * 64, k0 = blockIdx.y * 64;
    const int tr = threadIdx.x >> 4, tc = threadIdx.x & 15;
#pragma unroll
    for (int it = 0; it < 4; it++) {
        const int r = it * 16 + tr;   // k offset
        const float4 v = *reinterpret_cast<const float4*>(&src[(size_t)(k0 + r) * 512 + n0 + tc * 4]);
        tile[r][tc * 4 + 0] = v.x; tile[r][tc * 4 + 1] = v.y;
        tile[r][tc * 4 + 2] = v.z; tile[r][tc * 4 + 3] = v.w;
    }
    __syncthreads();
#pragma unroll
    for (int it = 0; it < 4; it++) {
        const int r = it * 16 + tr;   // n offset
        ushort4 o;
        o.x = f2bf(tile[tc * 4 + 0][r]); o.y = f2bf(tile[tc * 4 + 1][r]);
        o.z = f2bf(tile[tc * 4 + 2][r]); o.w = f2bf(tile[tc * 4 + 3][r]);
        *reinterpret_cast<ushort4*>(&dst[(size_t)(n0 + r) * 512 + k0 + tc * 4]) = o;
    }
}

// ---------------- sigma -> l2r = log2(r) --------------------------------------
__global__ __launch_bounds__(256) void sigma_kernel(const float* __restrict__ x,
                                                    const float* __restrict__ Ws,
                                                    const float* __restrict__ bs,
                                                    float* __restrict__ l2rbuf) {
    const int gid = blockIdx.x * 256 + threadIdx.x;   // row*8 + h
    const int row = gid >> 3;
    const int h = gid & 7;
    const float4* xr = reinterpret_cast<const float4*>(x + (size_t)row * D);
    float acc = 0.f;
#pragma unroll 4
    for (int e4 = 0; e4 < D / 4; e4++) {
        const float4 v = xr[e4];
        acc += v.x * Ws[(e4 * 4 + 0) * H + h] + v.y * Ws[(e4 * 4 + 1) * H + h]
             + v.z * Ws[(e4 * 4 + 2) * H + h] + v.w * Ws[(e4 * 4 + 3) * H + h];
    }
    const float z = acc + bs[h];
    const float sig = 1.0f / (1.0f + expf(-z));
    const float s = expf(sig) + 1.0f;
    l2rbuf[gid] = -1.4426950408889634f / s;   // log2(r), r = exp(-1/s)
}

// ---------------- bf16 MFMA GEMM: C[M,Nn] = A[M,K] @ Bt[Nn,K]^T (+bias) -------
#define GBM 128
#define GBN 64
#define GBK 64

__global__ __launch_bounds__(256) void gemm_bf16(const unsigned short* __restrict__ A,
                                                 const unsigned short* __restrict__ Bt,
                                                 const float* __restrict__ bias,
                                                 float* __restrict__ C,
                                                 int M, int Nn, int K) {
    __shared__ unsigned short As[GBM][GBK];   // 16 KB
    __shared__ unsigned short Bs[GBN][GBK];   // 8 KB
    const int tid = threadIdx.x;
    const int lane = tid & 63, wid = tid >> 6;
    const int wr = wid >> 1, wc = wid & 1;    // 2x2 waves: 64x32 each
    const int bm = blockIdx.y, bn = blockIdx.x;
    const int fr = lane & 15, kg = lane >> 4;

    f32x4 acc[4][2] = {};

    const unsigned short* Ab = A + (size_t)bm * GBM * K;
    const unsigned short* Bb = Bt + (size_t)bn * GBN * K;
    const int r8 = tid >> 3, c8 = (tid & 7) * 8;

    for (int k0 = 0; k0 < K; k0 += GBK) {
#pragma unroll
        for (int it = 0; it < 4; it++) {
            const unsigned short* g = Ab + (size_t)(it * 32 + r8) * K + k0 + c8;
            __builtin_amdgcn_global_load_lds(
                (const __attribute__((address_space(1))) void*)g,
                (__attribute__((address_space(3))) void*)&As[it * 32 + r8][c8], 16, 0, 0);
        }
#pragma unroll
        for (int it = 0; it < 2; it++) {
            const unsigned short* g = Bb + (size_t)(it * 32 + r8) * K + k0 + c8;
            __builtin_amdgcn_global_load_lds(
                (const __attribute__((address_space(1))) void*)g,
                (__attribute__((address_space(3))) void*)&Bs[it * 32 + r8][c8], 16, 0, 0);
        }
        __syncthreads();

#pragma unroll
        for (int ks = 0; ks < 2; ks++) {
            bf16x8 af[4], bfr[2];
#pragma unroll
            for (int m = 0; m < 4; m++)
                af[m] = *reinterpret_cast<const bf16x8*>(&As[wr * 64 + m * 16 + fr][ks * 32 + kg * 8]);
#pragma unroll
            for (int n = 0; n < 2; n++)
                bfr[n] = *reinterpret_cast<const bf16x8*>(&Bs[wc * 32 + n * 16 + fr][ks * 32 + kg * 8]);
#pragma unroll
            for (int m = 0; m < 4; m++)
#pragma unroll
                for (int n = 0; n < 2; n++)
                    acc[m][n] = __builtin_amdgcn_mfma_f32_16x16x32_bf16(af[m], bfr[n], acc[m][n], 0, 0, 0);
        }
        __syncthreads();
    }

#pragma unroll
    for (int n = 0; n < 2; n++) {
        const int col = bn * GBN + wc * 32 + n * 16 + fr;
        const float bv = bias ? bias[col] : 0.0f;
#pragma unroll
        for (int m = 0; m < 4; m++) {
            const int row0 = bm * GBM + wr * 64 + m * 16 + kg * 4;
#pragma unroll
            for (int j = 0; j < 4; j++)
                C[(size_t)(row0 + j) * Nn + col] = acc[m][n][j] + bv;
        }
    }
}

// ---------------- j-sweep windowed attention, 8 query rows per wave -----------
// weights wave-uniform; lane = dh index; 1-deep software prefetch in A/C phases
__global__ __launch_bounds__(256) void attn_sweep(const float* __restrict__ V,
                                                  const float* __restrict__ l2rbuf,
                                                  unsigned short* __restrict__ O) {
    const int wid = threadIdx.x >> 6;
    const int lane = threadIdx.x & 63;
    const int gi = blockIdx.x * 4 + wid;       // over (b,h,iblk)
    const int NB = N / QB;                     // 256
    const int iblk = gi % NB;
    const int bh = gi / NB;
    const int h = bh % H;
    const int b = bh / H;
    const int i0 = iblk * QB;

    const float* __restrict__ Vb = V + (size_t)b * N * D + h * DH + lane;

    float l2r[QB], r[QB], rinv[QB], w[QB], acc[QB];
#pragma unroll
    for (int k = 0; k < QB; k++) {
        l2r[k] = l2rbuf[((size_t)(b * N + i0 + k)) * H + h];
        r[k] = exp2f(l2r[k]);
        rinv[k] = exp2f(-l2r[k]);
        acc[k] = 0.f;
    }

    const int jA0 = (i0 >= WIN) ? (i0 - WIN) : 0;
    const int e0 = i0 - jA0;
#pragma unroll
    for (int k = 0; k < QB; k++) w[k] = exp2f(l2r[k] * (float)(e0 + k));

    const float* p = Vb + (size_t)jA0 * D;

    // Phase A: all j < i0 (prefetched)
    {
        int nA = i0 - jA0;
        if (nA > 0) {
            float vcur = *p; p += D;
            for (int j = 1; j < nA; ++j) {
                const float vnext = *p; p += D;
#pragma unroll
                for (int k = 0; k < QB; k++) { acc[k] += w[k] * vcur; w[k] *= rinv[k]; }
                vcur = vnext;
            }
#pragma unroll
            for (int k = 0; k < QB; k++) { acc[k] += w[k] * vcur; w[k] *= rinv[k]; }
        }
    }

    // Phase B: QB mixed steps, fully unrolled (j==i exact w=1 reset)
#pragma unroll
    for (int jj = 0; jj < QB; jj++) {
        const float v = *p; p += D;
#pragma unroll
        for (int k = 0; k < QB; k++) {
            if (jj == k)      { acc[k] += v;        w[k] = r[k];     }
            else if (jj < k)  { acc[k] += w[k] * v; w[k] *= rinv[k]; }
            else              { acc[k] += w[k] * v; w[k] *= r[k];    }
        }
    }

    // Phase C: all j > i0+QB-1 (prefetched)
    {
        const int jCend = (i0 + QB + WIN < N) ? (i0 + QB + WIN) : N;
        int nC = jCend - (i0 + QB);
        if (nC > 0) {
            float vcur = *p; p += D;
            for (int j = 1; j < nC; ++j) {
                const float vnext = *p; p += D;
#pragma unroll
                for (int k = 0; k < QB; k++) { acc[k] += w[k] * vcur; w[k] *= r[k]; }
                vcur = vnext;
            }
#pragma unroll
            for (int k = 0; k < QB; k++) { acc[k] += w[k] * vcur; }
        }
    }

    // closed-form softmax denominator
#pragma unroll
    for (int k = 0; k < QB; k++) {
        const int i = i0 + k;
        const float rr = r[k];
        const float inv1mr = 1.0f / (1.0f - rr);
        const float rl = exp2f(l2r[k] * (float)(i + 1));
        const float rg = exp2f(l2r[k] * (float)(N - i));
        const float z = 1.0f + (rr - rl) * inv1mr + (rr - rg) * inv1mr;
        O[((size_t)(b * N + i)) * D + h * DH + lane] = f2bf(acc[k] / z);
    }
}

extern "C" void kernel_launch(void* const* d_in, const int* in_sizes, int n_in,
                              void* d_out, int out_size, void* d_ws, size_t ws_size,
                              hipStream_t stream) {
    const float* x      = (const float*)d_in[0];   // (B,N,D)
    const float* W_v    = (const float*)d_in[1];   // (D, 512)
    const float* W_sig  = (const float*)d_in[2];   // (D, H)
    const float* b_sig  = (const float*)d_in[3];   // (H,)
    const float* W_out  = (const float*)d_in[4];   // (512, D)
    const float* b_out  = (const float*)d_in[5];   // (D,)
    float* out = (float*)d_out;

    char* ws = (char*)d_ws;
    float*          V    = (float*)ws;                                  // 16 MB
    unsigned short* xbf  = (unsigned short*)(ws + (size_t)16 * 1024 * 1024);  // 8 MB (reused as attnOut)
    unsigned short* WvT  = (unsigned short*)(ws + (size_t)24 * 1024 * 1024);  // 512 KB
    unsigned short* WoT  = (unsigned short*)(ws + (size_t)24 * 1024 * 1024 + 524288);
    float*          l2r  = (float*)(ws + (size_t)25 * 1024 * 1024);     // 256 KB
    unsigned short* attnOut = xbf;   // x_bf dead after GEMM1

    // prep: x->bf16, W transposes, sigma
    cvt_x<<<ROWS * D / (256 * 8), 256, 0, stream>>>(x, xbf);
    {
        dim3 grid(8, 8, 2);
        transpose_cvt<<<grid, 256, 0, stream>>>(W_v, W_out, WvT, WoT);
    }
    sigma_kernel<<<ROWS * H / 256, 256, 0, stream>>>(x, W_sig, b_sig, l2r);

    // 1) V = x @ W_v  (f32 out)
    {
        dim3 grid(D / GBN, ROWS / GBM);
        gemm_bf16<<<grid, 256, 0, stream>>>(xbf, WvT, nullptr, V, ROWS, D, D);
    }
    // 2) windowed attention -> bf16
    attn_sweep<<<B * H * (N / QB) / 4, 256, 0, stream>>>(V, l2r, attnOut);
    // 3) out = attnOut @ W_out + b_out
    {
        dim3 grid(D / GBN, ROWS / GBM);
        gemm_bf16<<<grid, 256, 0, stream>>>(attnOut, WoT, b_out, out, ROWS, D, D);
    }
}

// Round 5
// 95.065 us; speedup vs baseline: 1.4123x; 1.4123x over previous
//
#include <hip/hip_runtime.h>
#include <hip/hip_bf16.h>

// Problem constants
#define B 4
#define N 2048
#define D 512
#define H 8
#define DH 64
#define ROWS (B * N)        // 8192
#define WIN 64              // r<=0.764 -> r^64 ~ 3e-8
#define QB 8                // query rows per wave in attn_sweep

using bf16x8 = __attribute__((ext_vector_type(8))) short;  // 8 bf16 (4 VGPRs)
using f32x4  = __attribute__((ext_vector_type(4))) float;

static __device__ __forceinline__ unsigned short f2bf(float f) {
    unsigned u = __builtin_bit_cast(unsigned, f);
    u += 0x7fffu + ((u >> 16) & 1u);        // round-to-nearest-even
    return (unsigned short)(u >> 16);
}

// ---------------- x f32 -> bf16 (8 elems/thread) ------------------------------
__global__ __launch_bounds__(256) void cvt_x(const float* __restrict__ x,
                                             unsigned short* __restrict__ xbf) {
    const size_t t = (size_t)blockIdx.x * 256 + threadIdx.x;
    const float4* p = reinterpret_cast<const float4*>(x) + t * 2;
    const float4 a = p[0], b = p[1];
    ushort4 lo, hi;
    lo.x = f2bf(a.x); lo.y = f2bf(a.y); lo.z = f2bf(a.z); lo.w = f2bf(a.w);
    hi.x = f2bf(b.x); hi.y = f2bf(b.y); hi.z = f2bf(b.z); hi.w = f2bf(b.w);
    ushort4* q = reinterpret_cast<ushort4*>(xbf) + t * 2;
    q[0] = lo; q[1] = hi;
}

// ---------------- W (512x512 f32, KxN) -> W^T (NxK bf16) ----------------------
__global__ __launch_bounds__(256) void transpose_cvt(const float* __restrict__ Wv,
                                                     const float* __restrict__ Wo,
                                                     unsigned short* __restrict__ WvT,
                                                     unsigned short* __restrict__ WoT) {
    const float* src = blockIdx.z ? Wo : Wv;
    unsigned short* dst = blockIdx.z ? WoT : WvT;
    __shared__ float tile[64][65];
    const int n0 = blockIdx.x * 64, k0 = blockIdx.y * 64;
    const int tr = threadIdx.x >> 4, tc = threadIdx.x & 15;
#pragma unroll
    for (int it = 0; it < 4; it++) {
        const int r = it * 16 + tr;   // k offset
        const float4 v = *reinterpret_cast<const float4*>(&src[(size_t)(k0 + r) * 512 + n0 + tc * 4]);
        tile[r][tc * 4 + 0] = v.x; tile[r][tc * 4 + 1] = v.y;
        tile[r][tc * 4 + 2] = v.z; tile[r][tc * 4 + 3] = v.w;
    }
    __syncthreads();
#pragma unroll
    for (int it = 0; it < 4; it++) {
        const int r = it * 16 + tr;   // n offset
        ushort4 o;
        o.x = f2bf(tile[tc * 4 + 0][r]); o.y = f2bf(tile[tc * 4 + 1][r]);
        o.z = f2bf(tile[tc * 4 + 2][r]); o.w = f2bf(tile[tc * 4 + 3][r]);
        *reinterpret_cast<ushort4*>(&dst[(size_t)(n0 + r) * 512 + k0 + tc * 4]) = o;
    }
}

// ---------------- sigma -> l2r = log2(r) --------------------------------------
__global__ __launch_bounds__(256) void sigma_kernel(const float* __restrict__ x,
                                                    const float* __restrict__ Ws,
                                                    const float* __restrict__ bs,
                                                    float* __restrict__ l2rbuf) {
    const int gid = blockIdx.x * 256 + threadIdx.x;   // row*8 + h
    const int row = gid >> 3;
    const int h = gid & 7;
    const float4* xr = reinterpret_cast<const float4*>(x + (size_t)row * D);
    float acc = 0.f;
#pragma unroll 4
    for (int e4 = 0; e4 < D / 4; e4++) {
        const float4 v = xr[e4];
        acc += v.x * Ws[(e4 * 4 + 0) * H + h] + v.y * Ws[(e4 * 4 + 1) * H + h]
             + v.z * Ws[(e4 * 4 + 2) * H + h] + v.w * Ws[(e4 * 4 + 3) * H + h];
    }
    const float z = acc + bs[h];
    const float sig = 1.0f / (1.0f + expf(-z));
    const float s = expf(sig) + 1.0f;
    l2rbuf[gid] = -1.4426950408889634f / s;   // log2(r), r = exp(-1/s)
}

// ---------------- bf16 MFMA GEMM: C[M,Nn] = A[M,K] @ Bt[Nn,K]^T (+bias) -------
#define GBM 128
#define GBN 64
#define GBK 64

__global__ __launch_bounds__(256) void gemm_bf16(const unsigned short* __restrict__ A,
                                                 const unsigned short* __restrict__ Bt,
                                                 const float* __restrict__ bias,
                                                 float* __restrict__ C,
                                                 int M, int Nn, int K) {
    __shared__ unsigned short As[GBM][GBK];   // 16 KB
    __shared__ unsigned short Bs[GBN][GBK];   // 8 KB
    const int tid = threadIdx.x;
    const int lane = tid & 63, wid = tid >> 6;
    const int wr = wid >> 1, wc = wid & 1;    // 2x2 waves: 64x32 each
    const int bm = blockIdx.y, bn = blockIdx.x;
    const int fr = lane & 15, kg = lane >> 4;

    f32x4 acc[4][2] = {};

    const unsigned short* Ab = A + (size_t)bm * GBM * K;
    const unsigned short* Bb = Bt + (size_t)bn * GBN * K;
    const int r8 = tid >> 3, c8 = (tid & 7) * 8;

    for (int k0 = 0; k0 < K; k0 += GBK) {
#pragma unroll
        for (int it = 0; it < 4; it++) {
            const unsigned short* g = Ab + (size_t)(it * 32 + r8) * K + k0 + c8;
            __builtin_amdgcn_global_load_lds(
                (const __attribute__((address_space(1))) void*)g,
                (__attribute__((address_space(3))) void*)&As[it * 32 + r8][c8], 16, 0, 0);
        }
#pragma unroll
        for (int it = 0; it < 2; it++) {
            const unsigned short* g = Bb + (size_t)(it * 32 + r8) * K + k0 + c8;
            __builtin_amdgcn_global_load_lds(
                (const __attribute__((address_space(1))) void*)g,
                (__attribute__((address_space(3))) void*)&Bs[it * 32 + r8][c8], 16, 0, 0);
        }
        __syncthreads();

#pragma unroll
        for (int ks = 0; ks < 2; ks++) {
            bf16x8 af[4], bfr[2];
#pragma unroll
            for (int m = 0; m < 4; m++)
                af[m] = *reinterpret_cast<const bf16x8*>(&As[wr * 64 + m * 16 + fr][ks * 32 + kg * 8]);
#pragma unroll
            for (int n = 0; n < 2; n++)
                bfr[n] = *reinterpret_cast<const bf16x8*>(&Bs[wc * 32 + n * 16 + fr][ks * 32 + kg * 8]);
#pragma unroll
            for (int m = 0; m < 4; m++)
#pragma unroll
                for (int n = 0; n < 2; n++)
                    acc[m][n] = __builtin_amdgcn_mfma_f32_16x16x32_bf16(af[m], bfr[n], acc[m][n], 0, 0, 0);
        }
        __syncthreads();
    }

#pragma unroll
    for (int n = 0; n < 2; n++) {
        const int col = bn * GBN + wc * 32 + n * 16 + fr;
        const float bv = bias ? bias[col] : 0.0f;
#pragma unroll
        for (int m = 0; m < 4; m++) {
            const int row0 = bm * GBM + wr * 64 + m * 16 + kg * 4;
#pragma unroll
            for (int j = 0; j < 4; j++)
                C[(size_t)(row0 + j) * Nn + col] = acc[m][n][j] + bv;
        }
    }
}

// ---------------- j-sweep attention: 4 j-rows per float4 load-step ------------
// lane = g*16+q: g picks j within 4-row group, q covers dh via float4.
// Weights per-lane; phases A/C use running *= r^{+-4}; B uses direct exp2.
__global__ __launch_bounds__(256) void attn_sweep(const float* __restrict__ V,
                                                  const float* __restrict__ l2rbuf,
                                                  unsigned short* __restrict__ O) {
    const int wid = threadIdx.x >> 6;
    const int lane = threadIdx.x & 63;
    const int g = lane >> 4;            // j sub-offset 0..3
    const int q = lane & 15;            // dh quad 0..15
    const int gi = blockIdx.x * 4 + wid;       // over (b,h,iblk)
    const int NB = N / QB;                     // 256
    const int iblk = gi % NB;
    const int bh = gi / NB;
    const int h = bh & 7;
    const int b = bh >> 3;
    const int i0 = iblk * QB;

    const float* __restrict__ Vb = V + (size_t)b * N * D + h * DH + q * 4;

    float l2r[QB];
#pragma unroll
    for (int k = 0; k < QB; k++)
        l2r[k] = l2rbuf[((size_t)(b * N + i0 + k)) * H + h];

    f32x4 acc[QB];
#pragma unroll
    for (int k = 0; k < QB; k++) acc[k] = (f32x4)0.0f;

    const int jL = (i0 >= WIN) ? (i0 - WIN) : 0;                     // 4-aligned
    const int jR = (i0 + QB + WIN <= N) ? (i0 + QB + WIN) : N;       // 4-aligned
    const int nA = (i0 - jL) >> 2;
    const int nC = (jR - i0 - QB) >> 2;
    const size_t stepD = (size_t)4 * D;

    const float* p = Vb + (size_t)(jL + g) * D;

    // Phase A: j < i0, dist = i_k - j, shrink by 4 per step
    if (nA > 0) {
        float w[QB], rinv4[QB];
#pragma unroll
        for (int k = 0; k < QB; k++) {
            w[k] = exp2f(l2r[k] * (float)(i0 + k - jL - g));
            rinv4[k] = exp2f(-4.0f * l2r[k]);
        }
        f32x4 vc = *reinterpret_cast<const f32x4*>(p);
        for (int s = 1; s < nA; ++s) {
            const f32x4 vn = *reinterpret_cast<const f32x4*>(p + (size_t)s * stepD);
#pragma unroll
            for (int k = 0; k < QB; k++) { acc[k] += w[k] * vc; w[k] *= rinv4[k]; }
            vc = vn;
        }
#pragma unroll
        for (int k = 0; k < QB; k++) acc[k] += w[k] * vc;
        p += (size_t)nA * stepD;
    }

    // Phase B: 2 steps covering j in [i0, i0+8); direct exp2 weights (exp2(0)=1)
#pragma unroll
    for (int sb = 0; sb < 2; ++sb) {
        const int j = i0 + sb * 4 + g;
        const f32x4 v = *reinterpret_cast<const f32x4*>(p + (size_t)sb * stepD);
#pragma unroll
        for (int k = 0; k < QB; k++) {
            const int i = i0 + k;
            const int d = (j > i) ? (j - i) : (i - j);
            acc[k] += exp2f(l2r[k] * (float)d) * v;
        }
    }
    p += 2 * stepD;

    // Phase C: j >= i0+8, dist = j - i_k, grow by 4 per step
    if (nC > 0) {
        float w[QB], r4[QB];
#pragma unroll
        for (int k = 0; k < QB; k++) {
            w[k] = exp2f(l2r[k] * (float)(QB + g - k));
            r4[k] = exp2f(4.0f * l2r[k]);
        }
        f32x4 vc = *reinterpret_cast<const f32x4*>(p);
        for (int s = 1; s < nC; ++s) {
            const f32x4 vn = *reinterpret_cast<const f32x4*>(p + (size_t)s * stepD);
#pragma unroll
            for (int k = 0; k < QB; k++) { acc[k] += w[k] * vc; w[k] *= r4[k]; }
            vc = vn;
        }
#pragma unroll
        for (int k = 0; k < QB; k++) acc[k] += w[k] * vc;
    }

    // cross-group reduce (lanes l, l+16, l+32, l+48 hold partial sums)
#pragma unroll
    for (int k = 0; k < QB; k++) {
#pragma unroll
        for (int c = 0; c < 4; c++) {
            float t = acc[k][c];
            t += __shfl_xor(t, 16, 64);
            t += __shfl_xor(t, 32, 64);
            acc[k][c] = t;
        }
    }

    // closed-form softmax denominator; group g stores k with k%4 == g
#pragma unroll
    for (int k = 0; k < QB; k++) {
        if ((k & 3) == g) {
            const int i = i0 + k;
            const float rr = exp2f(l2r[k]);
            const float inv1mr = 1.0f / (1.0f - rr);
            const float rl = exp2f(l2r[k] * (float)(i + 1));
            const float rg = exp2f(l2r[k] * (float)(N - i));
            const float z = 1.0f + (rr - rl) * inv1mr + (rr - rg) * inv1mr;
            const float invz = 1.0f / z;
            ushort4 o;
            o.x = f2bf(acc[k][0] * invz); o.y = f2bf(acc[k][1] * invz);
            o.z = f2bf(acc[k][2] * invz); o.w = f2bf(acc[k][3] * invz);
            *reinterpret_cast<ushort4*>(&O[((size_t)(b * N + i)) * D + h * DH + q * 4]) = o;
        }
    }
}

extern "C" void kernel_launch(void* const* d_in, const int* in_sizes, int n_in,
                              void* d_out, int out_size, void* d_ws, size_t ws_size,
                              hipStream_t stream) {
    const float* x      = (const float*)d_in[0];   // (B,N,D)
    const float* W_v    = (const float*)d_in[1];   // (D, 512)
    const float* W_sig  = (const float*)d_in[2];   // (D, H)
    const float* b_sig  = (const float*)d_in[3];   // (H,)
    const float* W_out  = (const float*)d_in[4];   // (512, D)
    const float* b_out  = (const float*)d_in[5];   // (D,)
    float* out = (float*)d_out;

    char* ws = (char*)d_ws;
    float*          V    = (float*)ws;                                  // 16 MB
    unsigned short* xbf  = (unsigned short*)(ws + (size_t)16 * 1024 * 1024);  // 8 MB (reused as attnOut)
    unsigned short* WvT  = (unsigned short*)(ws + (size_t)24 * 1024 * 1024);  // 512 KB
    unsigned short* WoT  = (unsigned short*)(ws + (size_t)24 * 1024 * 1024 + 524288);
    float*          l2r  = (float*)(ws + (size_t)25 * 1024 * 1024);     // 256 KB
    unsigned short* attnOut = xbf;   // x_bf dead after GEMM1

    // prep: x->bf16, W transposes, sigma
    cvt_x<<<ROWS * D / (256 * 8), 256, 0, stream>>>(x, xbf);
    {
        dim3 grid(8, 8, 2);
        transpose_cvt<<<grid, 256, 0, stream>>>(W_v, W_out, WvT, WoT);
    }
    sigma_kernel<<<ROWS * H / 256, 256, 0, stream>>>(x, W_sig, b_sig, l2r);

    // 1) V = x @ W_v  (f32 out)
    {
        dim3 grid(D / GBN, ROWS / GBM);
        gemm_bf16<<<grid, 256, 0, stream>>>(xbf, WvT, nullptr, V, ROWS, D, D);
    }
    // 2) windowed attention -> bf16
    attn_sweep<<<B * H * (N / QB) / 4, 256, 0, stream>>>(V, l2r, attnOut);
    // 3) out = attnOut @ W_out + b_out
    {
        dim3 grid(D / GBN, ROWS / GBM);
        gemm_bf16<<<grid, 256, 0, stream>>>(attnOut, WoT, b_out, out, ROWS, D, D);
    }
}